// Round 1
// baseline (247.596 us; speedup 1.0000x reference)
//
#include <hip/hip_runtime.h>
#include <stdint.h>

#define BATCH    256
#define VOCAB    128000
#define HIST     200
#define TOPK     50
#define CAP      2048
#define NTHREADS 1024
#define BITWORDS (VOCAB / 32)   // 4000 words = 16000 B

// Monotonic float->uint key: descending float order == descending unsigned order.
__device__ __forceinline__ unsigned fkey_of(float f) {
  unsigned u = __float_as_uint(f);
  return (u & 0x80000000u) ? ~u : (u | 0x80000000u);
}
__device__ __forceinline__ float f_of_key(unsigned k) {
  unsigned u = (k & 0x80000000u) ? (k & 0x7FFFFFFFu) : ~k;
  return __uint_as_float(u);
}

__global__ __launch_bounds__(NTHREADS) void sample_head_kernel(
    const float* __restrict__ logits, const int* __restrict__ prev,
    float* __restrict__ out)
{
  __shared__ unsigned bitmask[BITWORDS];          // 16000 B
  __shared__ unsigned long long keys[CAP];        // 16384 B
  __shared__ float evals[CAP];                    //  8192 B
  __shared__ int s_count;
  __shared__ int s_m, s_j;
  __shared__ float s_maxx, s_Z2;

  const int b   = blockIdx.x;
  const int tid = threadIdx.x;
  const float* row  = logits + (size_t)b * VOCAB;
  float*       orow = out    + (size_t)b * VOCAB;

  // ---- seen-token bitmask ----
  for (int i = tid; i < BITWORDS; i += NTHREADS) bitmask[i] = 0u;
  __syncthreads();
  for (int i = tid; i < HIST; i += NTHREADS) {
    int t = prev[b * HIST + i];
    atomicOr(&bitmask[t >> 5], 1u << (t & 31));
  }
  __syncthreads();

  // ---- collect pass with threshold retry (bisection safety net) ----
  // T is in pre-temperature (y) space. y ~ N(0,1); kth@50/128000 ~= 3.36 sigma.
  float T = 3.0f;                 // expected count(y>T) ~= 173 in [TOPK, CAP]
  float Tlo = 0.f, Thi = 0.f;
  bool hasLo = false, hasHi = false;
  int cnt = 0;

  const float4* row4  = (const float4*)row;
  float4*       orow4 = (float4*)orow;
  const int N4 = VOCAB / 4;       // 32000

  for (int attempt = 0; attempt < 40; ++attempt) {
    __syncthreads();
    if (tid == 0) s_count = 0;
    __syncthreads();

    for (int i = tid; i < N4; i += NTHREADS) {
      float4 v4 = row4[i];
      if (attempt == 0) orow4[i] = make_float4(0.f, 0.f, 0.f, 0.f);
      int v0 = i * 4;
      unsigned w  = bitmask[v0 >> 5];
      unsigned sh = v0 & 31;
      float vv[4] = {v4.x, v4.y, v4.z, v4.w};
      #pragma unroll
      for (int l = 0; l < 4; ++l) {
        float v = vv[l];
        float y = v;
        if ((w >> (sh + l)) & 1u)                       // repetition penalty (rare)
          y = (v < 0.0f) ? v * 1.2f : v / 1.2f;
        if (y > T) {                                    // superset of top-k set
          float x = y / 0.6f;                           // temperature (exact IEEE div)
          int pos = atomicAdd(&s_count, 1);
          if (pos < CAP) {
            unsigned k = fkey_of(x);
            keys[pos] = ((unsigned long long)k << 32) |
                        (unsigned)(~(unsigned)(v0 + l)); // tie-break: smaller idx first
          }
        }
      }
    }
    __syncthreads();
    cnt = s_count;
    if (cnt >= TOPK && cnt <= CAP) break;
    if (cnt < TOPK) { Thi = T; hasHi = true; T = hasLo ? 0.5f * (T + Tlo) : T - 1.0f; }
    else            { Tlo = T; hasLo = true; T = hasHi ? 0.5f * (T + Thi) : T + 1.0f; }
  }
  if (cnt > CAP) cnt = CAP;   // pathological-tie fallback (never for this input)

  // ---- bitonic sort descending, padded to pow2 ----
  int n = 64;
  while (n < cnt) n <<= 1;
  for (int i = cnt + tid; i < n; i += NTHREADS) keys[i] = 0ull;
  __syncthreads();
  for (int k = 2; k <= n; k <<= 1) {
    for (int j = k >> 1; j > 0; j >>= 1) {
      for (int i = tid; i < n; i += NTHREADS) {
        int l = i ^ j;
        if (l > i) {
          unsigned long long a = keys[i], c = keys[l];
          bool up = (i & k) == 0;
          if (up ? (a < c) : (a > c)) { keys[i] = c; keys[l] = a; }
        }
      }
      __syncthreads();
    }
  }

  // ---- top-k boundary (keep ties at kth) + max ----
  if (tid == 0) {
    int kk = (cnt < TOPK) ? cnt : TOPK;
    unsigned kth = (unsigned)(keys[kk - 1] >> 32);
    int m = kk;
    while (m < cnt && (unsigned)(keys[m] >> 32) == kth) m++;
    s_m = m;
    s_maxx = f_of_key((unsigned)(keys[0] >> 32));
  }
  __syncthreads();
  int m = s_m;
  float maxx = s_maxx;
  for (int i = tid; i < m; i += NTHREADS)
    evals[i] = expf(f_of_key((unsigned)(keys[i] >> 32)) - maxx);
  __syncthreads();

  // ---- nucleus cutoff: keep token i iff i==0 or cumsum(p[0..i-1]) <= 0.9 ----
  if (tid == 0) {
    float Z = 0.f;
    for (int i = 0; i < m; ++i) Z += evals[i];
    float cum = 0.f;
    int j = 0;
    for (int i = 0; i < m; ++i) {
      if (i > 0 && cum > 0.9f) break;
      cum += evals[i] / Z;
      j = i + 1;
    }
    float Z2 = 0.f;
    for (int i = 0; i < j; ++i) Z2 += evals[i];
    s_j = j; s_Z2 = Z2;
  }
  __syncthreads();

  // ---- scatter final probs (row already zeroed) ----
  int j = s_j;
  float Z2 = s_Z2;
  for (int i = tid; i < j; i += NTHREADS) {
    int idx = (int)(~(unsigned)(keys[i] & 0xFFFFFFFFull));
    orow[idx] = evals[i] / Z2;
  }
}

extern "C" void kernel_launch(void* const* d_in, const int* in_sizes, int n_in,
                              void* d_out, int out_size, void* d_ws, size_t ws_size,
                              hipStream_t stream) {
  const float* logits = (const float*)d_in[0];
  const int*   prev   = (const int*)d_in[1];
  float*       out    = (float*)d_out;
  hipLaunchKernelGGL(sample_head_kernel, dim3(BATCH), dim3(NTHREADS), 0, stream,
                     logits, prev, out);
}